// Round 3
// baseline (624.290 us; speedup 1.0000x reference)
//
#include <hip/hip_runtime.h>
#include <stdint.h>

// Problem constants
#define B_   8
#define C_   256
#define N_   2304          // 48*48 spatial
#define HID  128
#define O3   384           // 3*HID
#define NH   4
#define SCALE 0.0625f      // 256^-0.5

typedef unsigned short u16;
typedef short  bf8  __attribute__((ext_vector_type(8)));   // 8 bf16 (4 VGPRs) MFMA A/B frag
typedef float  f4   __attribute__((ext_vector_type(4)));   // MFMA C/D frag
typedef u16    u16x8 __attribute__((ext_vector_type(8)));

#define MFMA(a,b,c) __builtin_amdgcn_mfma_f32_16x16x32_bf16((a),(b),(c),0,0,0)

static __device__ __forceinline__ u16 f2bf(float f){
    union { float f; unsigned int i; } v; v.f = f;
    unsigned int r = v.i + 0x7FFFu + ((v.i >> 16) & 1u);   // round-to-nearest-even
    return (u16)(r >> 16);
}

// ---------------------------------------------------------------------------
// K0a: convert embed weights fp32 -> bf16.  ew[s] is 384*256 = 98304 elems.
__global__ __launch_bounds__(256) void k_wcvt(const float* __restrict__ w0,
                                              const float* __restrict__ w1,
                                              u16* __restrict__ Wbf){
    int s = blockIdx.y;
    const float* w = s ? w1 : w0;
    u16* o = Wbf + (size_t)s * (O3 * C_);
    int idx = (blockIdx.x * 256 + threadIdx.x) * 4;        // 96 blocks * 1024
    float4 v = *reinterpret_cast<const float4*>(&w[idx]);
    o[idx+0] = f2bf(v.x); o[idx+1] = f2bf(v.y);
    o[idx+2] = f2bf(v.z); o[idx+3] = f2bf(v.w);
}

// K0b: w_eff^T[s][oc][hc] = sum_head out_w_s[head*HID+hc][oc]  (heads identical)
__global__ void k_weff(const float* __restrict__ w0, const float* __restrict__ w1,
                       u16* __restrict__ weff){
    int s = blockIdx.x;
    const float* w = s ? w1 : w0;
    int oc = threadIdx.x;
    for (int hc = 0; hc < HID; ++hc){
        float acc = 0.f;
        #pragma unroll
        for (int h = 0; h < NH; ++h) acc += w[(h*HID + hc)*C_ + oc];
        weff[(s*C_ + oc)*HID + hc] = f2bf(acc);
    }
}

// ---------------------------------------------------------------------------
// K1a: transpose+convert X[bs][c][n] fp32 -> Xt[bs][n][c] bf16 (Xt in d_out)
__global__ __launch_bounds__(256) void k_transpose(const float* __restrict__ x0,
                                                   const float* __restrict__ x1,
                                                   u16* __restrict__ Xt){
    __shared__ __align__(16) u16 tile[64][72];   // +8 pad breaks bank conflicts
    int z = blockIdx.z, b = z >> 1, s = z & 1;
    const float* X = (s ? x1 : x0) + (size_t)b * (C_ * N_);
    u16* out = Xt + (size_t)z * (N_ * C_);
    int n0 = blockIdx.x * 64, c0 = blockIdx.y * 64;
    int t = threadIdx.x;
    // load: 64 c-rows x 64 n-cols fp32, convert to bf16 in LDS
    int lr = t >> 4, lc = (t & 15) * 4;          // 16 rows/pass x 16 lanes x 4 floats
    #pragma unroll
    for (int rep = 0; rep < 4; ++rep){
        int c = lr + rep * 16;
        float4 v = *reinterpret_cast<const float4*>(&X[(size_t)(c0 + c) * N_ + n0 + lc]);
        tile[c][lc+0] = f2bf(v.x); tile[c][lc+1] = f2bf(v.y);
        tile[c][lc+2] = f2bf(v.z); tile[c][lc+3] = f2bf(v.w);
    }
    __syncthreads();
    int row = t >> 3, col8 = (t & 7) * 8;
    #pragma unroll
    for (int rep = 0; rep < 2; ++rep){
        int n = row + rep * 32;
        u16x8 v;
        #pragma unroll
        for (int j = 0; j < 8; ++j) v[j] = tile[col8 + j][n];
        *reinterpret_cast<u16x8*>(&out[(size_t)(n0 + n) * C_ + c0 + col8]) = v;
    }
}

// ---------------------------------------------------------------------------
// K1b: embed GEMM  E[o][n] = Wbf[o][c] * Xt[n][c]^T + bias, scatter to Q/K/V.
//   Qt[bs][m][c] (c contig), Kt[bs][n][c] (c contig), Vl[bs][c][n] (n contig)
__global__ __launch_bounds__(256) void k_embed(const u16* __restrict__ Xt,
        const u16* __restrict__ Wbf,
        const float* __restrict__ b0, const float* __restrict__ b1,
        u16* __restrict__ Qt, u16* __restrict__ Kt, u16* __restrict__ Vl){
    int z = blockIdx.z, s = z & 1;
    const u16* W = Wbf + (size_t)s * (O3 * C_);
    const float* bias = s ? b1 : b0;
    const u16* Xb = Xt + (size_t)z * (N_ * C_);
    int lane = threadIdx.x & 63, wave = threadIdx.x >> 6;
    int l16 = lane & 15, quad = lane >> 4;
    int o0 = blockIdx.y * 64 + wave * 16;
    int n0 = blockIdx.x * 64;
    f4 acc[4] = {f4{0,0,0,0}, f4{0,0,0,0}, f4{0,0,0,0}, f4{0,0,0,0}};
    #pragma unroll
    for (int kk = 0; kk < 8; ++kk){           // K = 256 = 8 * 32
        bf8 a = *reinterpret_cast<const bf8*>(&W[(o0 + l16) * C_ + kk*32 + quad*8]);
        #pragma unroll
        for (int nt = 0; nt < 4; ++nt){
            bf8 bb = *reinterpret_cast<const bf8*>(&Xb[(size_t)(n0 + nt*16 + l16) * C_ + kk*32 + quad*8]);
            acc[nt] = MFMA(a, bb, acc[nt]);
        }
    }
    // epilogue: D[o = o0+quad*4+r][n = n0+nt*16+l16]
    #pragma unroll
    for (int nt = 0; nt < 4; ++nt){
        int n = n0 + nt*16 + l16;
        #pragma unroll
        for (int r = 0; r < 4; ++r){
            int o = o0 + quad*4 + r;
            u16 hv = f2bf(acc[nt][r] + bias[o]);
            if (o < HID)            Qt[((size_t)z*N_ + n)*HID + o] = hv;
            else if (o < 2*HID)     Kt[((size_t)z*N_ + n)*HID + (o - HID)] = hv;
            else                    Vl[((size_t)z*HID + (o - 2*HID))*N_ + n] = hv;
        }
    }
}

// ---------------------------------------------------------------------------
// K2 (fused): flash attention + head-collapse output projection + residual.
//   stream s output: Q from stream (1-s), K/V from s.
__global__ __launch_bounds__(256) void k_attn_out(const u16* __restrict__ Qt,
        const u16* __restrict__ Kt, const u16* __restrict__ Vl,
        const u16* __restrict__ weff,
        const float* __restrict__ ob0, const float* __restrict__ ob1,
        const float* __restrict__ x0, const float* __restrict__ x1,
        float* __restrict__ out){
    __shared__ __align__(16) u16 p_lds[4][16][72];   // per-wave P tile (2-way, free)
    __shared__ __align__(16) u16 h_lds[64][136];     // H tile, +8 pad (2-way, free)
    int z = blockIdx.y, b = z >> 1, s = z & 1;
    const u16* Q = Qt + (size_t)(b*2 + (1 - s)) * (N_ * HID);
    const u16* K = Kt + (size_t)(b*2 + s)       * (N_ * HID);
    const u16* V = Vl + (size_t)(b*2 + s)       * ((size_t)HID * N_);
    const u16* Wf   = weff + (size_t)s * (C_ * HID);
    const float* bias = s ? ob1 : ob0;
    const float* X = (s ? x1 : x0) + (size_t)b * (C_ * N_);
    float* O = out + (size_t)s * ((size_t)B_ * C_ * N_) + (size_t)b * (C_ * N_);
    int lane = threadIdx.x & 63, wave = threadIdx.x >> 6;
    int l16 = lane & 15, quad = lane >> 4;
    int m0 = blockIdx.x * 64 + wave * 16;

    bf8 aq[4];
    #pragma unroll
    for (int kk = 0; kk < 4; ++kk)            // head dim 128 = 4 * 32
        aq[kk] = *reinterpret_cast<const bf8*>(&Q[(size_t)(m0 + l16)*HID + kk*32 + quad*8]);

    f4 oacc[8];
    #pragma unroll
    for (int ct = 0; ct < 8; ++ct) oacc[ct] = f4{0,0,0,0};
    float mrun[4], lrun[4];
    #pragma unroll
    for (int r = 0; r < 4; ++r){ mrun[r] = -1e30f; lrun[r] = 0.f; }

    for (int nc = 0; nc < N_/64; ++nc){
        int n0 = nc * 64;
        f4 sacc[4];
        #pragma unroll
        for (int nt = 0; nt < 4; ++nt) sacc[nt] = f4{0,0,0,0};
        #pragma unroll
        for (int kk = 0; kk < 4; ++kk){
            #pragma unroll
            for (int nt = 0; nt < 4; ++nt){
                bf8 bk = *reinterpret_cast<const bf8*>(&K[(size_t)(n0 + nt*16 + l16)*HID + kk*32 + quad*8]);
                sacc[nt] = MFMA(aq[kk], bk, sacc[nt]);
            }
        }
        // scale + row max (row m = m0+quad*4+r lives in 16 lanes x 4 regs(nt))
        float rmax[4];
        #pragma unroll
        for (int r = 0; r < 4; ++r){
            #pragma unroll
            for (int nt = 0; nt < 4; ++nt) sacc[nt][r] *= SCALE;
            float m_ = fmaxf(fmaxf(sacc[0][r], sacc[1][r]), fmaxf(sacc[2][r], sacc[3][r]));
            #pragma unroll
            for (int off = 8; off >= 1; off >>= 1) m_ = fmaxf(m_, __shfl_xor(m_, off, 16));
            rmax[r] = m_;
        }
        float alpha[4], rsum[4];
        #pragma unroll
        for (int r = 0; r < 4; ++r){
            float nm = fmaxf(mrun[r], rmax[r]);
            alpha[r] = __expf(mrun[r] - nm);
            mrun[r] = nm; rsum[r] = 0.f;
        }
        #pragma unroll
        for (int nt = 0; nt < 4; ++nt){
            #pragma unroll
            for (int r = 0; r < 4; ++r){
                float p = __expf(sacc[nt][r] - mrun[r]);
                rsum[r] += p;
                p_lds[wave][quad*4 + r][nt*16 + l16] = f2bf(p);
            }
        }
        #pragma unroll
        for (int r = 0; r < 4; ++r){
            float t = rsum[r];
            #pragma unroll
            for (int off = 8; off >= 1; off >>= 1) t += __shfl_xor(t, off, 16);
            lrun[r] = lrun[r]*alpha[r] + t;
            #pragma unroll
            for (int ct = 0; ct < 8; ++ct) oacc[ct][r] *= alpha[r];
        }
        // P (A-operand, per-wave LDS) @ V (B-operand, contiguous from Vl)
        #pragma unroll
        for (int kk2 = 0; kk2 < 2; ++kk2){
            bf8 ap = *reinterpret_cast<const bf8*>(&p_lds[wave][l16][kk2*32 + quad*8]);
            #pragma unroll
            for (int ct = 0; ct < 8; ++ct){
                bf8 bv = *reinterpret_cast<const bf8*>(&V[(size_t)(ct*16 + l16)*N_ + n0 + kk2*32 + quad*8]);
                oacc[ct] = MFMA(ap, bv, oacc[ct]);
            }
        }
    }
    // normalize + stash H tile [64 m][128 hc] to LDS (wave owns rows wave*16..+15)
    float inv[4];
    #pragma unroll
    for (int r = 0; r < 4; ++r) inv[r] = 1.0f / lrun[r];
    #pragma unroll
    for (int ct = 0; ct < 8; ++ct){
        #pragma unroll
        for (int r = 0; r < 4; ++r){
            h_lds[(m0 & 63) + quad*4 + r][ct*16 + l16] = f2bf(oacc[ct][r] * inv[r]);
        }
    }
    __syncthreads();

    // out GEMM: wave w handles oc in [w*64, w*64+64); K = HID = 128
    int mb = blockIdx.x * 64;                 // block's m base
    int oc0 = wave * 64;
    f4 acc2[4][4];
    #pragma unroll
    for (int ot = 0; ot < 4; ++ot)
        #pragma unroll
        for (int nt = 0; nt < 4; ++nt) acc2[ot][nt] = f4{0,0,0,0};
    #pragma unroll
    for (int kk = 0; kk < 4; ++kk){
        bf8 bh[4];
        #pragma unroll
        for (int nt = 0; nt < 4; ++nt)
            bh[nt] = *reinterpret_cast<const bf8*>(&h_lds[nt*16 + l16][kk*32 + quad*8]);
        #pragma unroll
        for (int ot = 0; ot < 4; ++ot){
            bf8 a = *reinterpret_cast<const bf8*>(&Wf[(oc0 + ot*16 + l16)*HID + kk*32 + quad*8]);
            #pragma unroll
            for (int nt = 0; nt < 4; ++nt)
                acc2[ot][nt] = MFMA(a, bh[nt], acc2[ot][nt]);
        }
    }
    #pragma unroll
    for (int ot = 0; ot < 4; ++ot){
        #pragma unroll
        for (int nt = 0; nt < 4; ++nt){
            int m = mb + nt*16 + l16;
            #pragma unroll
            for (int r = 0; r < 4; ++r){
                int oc = oc0 + ot*16 + quad*4 + r;
                float v = acc2[ot][nt][r] + bias[oc] + X[(size_t)oc*N_ + m];
                O[(size_t)oc*N_ + m] = v;
            }
        }
    }
}

// ---------------------------------------------------------------------------
extern "C" void kernel_launch(void* const* d_in, const int* in_sizes, int n_in,
                              void* d_out, int out_size, void* d_ws, size_t ws_size,
                              hipStream_t stream){
    const float* x0  = (const float*)d_in[0];
    const float* x1  = (const float*)d_in[1];
    const float* ew0 = (const float*)d_in[2];
    const float* eb0 = (const float*)d_in[3];
    const float* ew1 = (const float*)d_in[4];
    const float* eb1 = (const float*)d_in[5];
    const float* ow0 = (const float*)d_in[6];
    const float* ob0 = (const float*)d_in[7];
    const float* ow1 = (const float*)d_in[8];
    const float* ob1 = (const float*)d_in[9];

    // Workspace (bf16): Qt/Kt/Vl + converted weights  (~28.9 MiB).
    // Xt (bf16, 18.9 MiB) lives in d_out (fp32, 37.7 MiB) as scratch — dead
    // before k_attn_out rewrites d_out.
    u16* ws = (u16*)d_ws;
    const size_t QT_E = (size_t)16 * N_ * HID;    // 4,718,592 elems each
    u16* Qt   = ws;
    u16* Kt   = Qt + QT_E;
    u16* Vl   = Kt + QT_E;
    u16* Wbf  = Vl + QT_E;                        // 2*384*256 = 196,608 elems
    u16* weff = Wbf + (size_t)2 * O3 * C_;        // 2*256*128 =  65,536 elems
    u16* Xt   = (u16*)d_out;                      // scratch phase

    k_wcvt     <<<dim3(96, 2),     dim3(256), 0, stream>>>(ew0, ew1, Wbf);
    k_weff     <<<dim3(2),         dim3(256), 0, stream>>>(ow0, ow1, weff);
    k_transpose<<<dim3(36, 4, 16), dim3(256), 0, stream>>>(x0, x1, Xt);
    k_embed    <<<dim3(36, 6, 16), dim3(256), 0, stream>>>(Xt, Wbf, eb0, eb1, Qt, Kt, Vl);
    k_attn_out <<<dim3(36, 16),    dim3(256), 0, stream>>>(Qt, Kt, Vl, weff, ob0, ob1,
                                                           x0, x1, (float*)d_out);
}

// Round 4
// 589.243 us; speedup vs baseline: 1.0595x; 1.0595x over previous
//
#include <hip/hip_runtime.h>
#include <stdint.h>

// Problem constants
#define B_   8
#define C_   256
#define N_   2304          // 48*48 spatial
#define HID  128
#define O3   384           // 3*HID
#define NH   4
#define SCALE 0.0625f      // 256^-0.5
#define QPRE 0.09016844f   // SCALE * log2(e): q pre-scale so p = exp2(q.k)

typedef unsigned short u16;
typedef short  bf8  __attribute__((ext_vector_type(8)));   // 8 bf16 (4 VGPRs) MFMA A/B frag
typedef float  f4   __attribute__((ext_vector_type(4)));   // MFMA C/D frag
typedef u16    u16x8 __attribute__((ext_vector_type(8)));

#define MFMA(a,b,c) __builtin_amdgcn_mfma_f32_16x16x32_bf16((a),(b),(c),0,0,0)

static __device__ __forceinline__ u16 f2bf(float f){
    union { float f; unsigned int i; } v; v.f = f;
    unsigned int r = v.i + 0x7FFFu + ((v.i >> 16) & 1u);   // round-to-nearest-even
    return (u16)(r >> 16);
}
static __device__ __forceinline__ float fexp2(float x){
#if __has_builtin(__builtin_amdgcn_exp2f)
    return __builtin_amdgcn_exp2f(x);
#else
    return __expf(x * 0.69314718f);
#endif
}
static __device__ __forceinline__ u16 hi16(float f){       // truncating f32->bf16
    union { float f; unsigned int i; } v; v.f = f;
    return (u16)(v.i >> 16);
}

// ---------------------------------------------------------------------------
// K0a: convert embed weights fp32 -> bf16.
__global__ __launch_bounds__(256) void k_wcvt(const float* __restrict__ w0,
                                              const float* __restrict__ w1,
                                              u16* __restrict__ Wbf){
    int s = blockIdx.y;
    const float* w = s ? w1 : w0;
    u16* o = Wbf + (size_t)s * (O3 * C_);
    int idx = (blockIdx.x * 256 + threadIdx.x) * 4;
    float4 v = *reinterpret_cast<const float4*>(&w[idx]);
    o[idx+0] = f2bf(v.x); o[idx+1] = f2bf(v.y);
    o[idx+2] = f2bf(v.z); o[idx+3] = f2bf(v.w);
}

// K0b: w_eff^T[s][oc][hc] = sum_head out_w_s[head*HID+hc][oc]  (heads identical)
__global__ void k_weff(const float* __restrict__ w0, const float* __restrict__ w1,
                       u16* __restrict__ weff){
    int s = blockIdx.x;
    const float* w = s ? w1 : w0;
    int oc = threadIdx.x;
    for (int hc = 0; hc < HID; ++hc){
        float acc = 0.f;
        #pragma unroll
        for (int h = 0; h < NH; ++h) acc += w[(h*HID + hc)*C_ + oc];
        weff[(s*C_ + oc)*HID + hc] = f2bf(acc);
    }
}

// ---------------------------------------------------------------------------
// K1a: transpose+convert X[bs][c][n] fp32 -> Xt[bs][n][c] bf16 (Xt in d_out)
__global__ __launch_bounds__(256) void k_transpose(const float* __restrict__ x0,
                                                   const float* __restrict__ x1,
                                                   u16* __restrict__ Xt){
    __shared__ __align__(16) u16 tile[64][72];
    int z = blockIdx.z, b = z >> 1, s = z & 1;
    const float* X = (s ? x1 : x0) + (size_t)b * (C_ * N_);
    u16* out = Xt + (size_t)z * (N_ * C_);
    int n0 = blockIdx.x * 64, c0 = blockIdx.y * 64;
    int t = threadIdx.x;
    int lr = t >> 4, lc = (t & 15) * 4;
    #pragma unroll
    for (int rep = 0; rep < 4; ++rep){
        int c = lr + rep * 16;
        float4 v = *reinterpret_cast<const float4*>(&X[(size_t)(c0 + c) * N_ + n0 + lc]);
        tile[c][lc+0] = f2bf(v.x); tile[c][lc+1] = f2bf(v.y);
        tile[c][lc+2] = f2bf(v.z); tile[c][lc+3] = f2bf(v.w);
    }
    __syncthreads();
    int row = t >> 3, col8 = (t & 7) * 8;
    #pragma unroll
    for (int rep = 0; rep < 2; ++rep){
        int n = row + rep * 32;
        u16x8 v;
        #pragma unroll
        for (int j = 0; j < 8; ++j) v[j] = tile[col8 + j][n];
        *reinterpret_cast<u16x8*>(&out[(size_t)(n0 + n) * C_ + c0 + col8]) = v;
    }
}

// ---------------------------------------------------------------------------
// K1b: embed GEMM.  Q is PRE-SCALED by QPRE so attention uses exp2 directly.
__global__ __launch_bounds__(256, 2) void k_embed(const u16* __restrict__ Xt,
        const u16* __restrict__ Wbf,
        const float* __restrict__ b0, const float* __restrict__ b1,
        u16* __restrict__ Qt, u16* __restrict__ Kt, u16* __restrict__ Vl){
    int z = blockIdx.z, s = z & 1;
    const u16* W = Wbf + (size_t)s * (O3 * C_);
    const float* bias = s ? b1 : b0;
    const u16* Xb = Xt + (size_t)z * (N_ * C_);
    int lane = threadIdx.x & 63, wave = threadIdx.x >> 6;
    int l16 = lane & 15, quad = lane >> 4;
    int o0 = blockIdx.y * 64 + wave * 16;
    int n0 = blockIdx.x * 64;
    f4 acc[4] = {f4{0,0,0,0}, f4{0,0,0,0}, f4{0,0,0,0}, f4{0,0,0,0}};
    #pragma unroll
    for (int kk = 0; kk < 8; ++kk){           // K = 256 = 8 * 32
        bf8 a = *reinterpret_cast<const bf8*>(&W[(o0 + l16) * C_ + kk*32 + quad*8]);
        #pragma unroll
        for (int nt = 0; nt < 4; ++nt){
            bf8 bb = *reinterpret_cast<const bf8*>(&Xb[(size_t)(n0 + nt*16 + l16) * C_ + kk*32 + quad*8]);
            acc[nt] = MFMA(a, bb, acc[nt]);
        }
    }
    #pragma unroll
    for (int nt = 0; nt < 4; ++nt){
        int n = n0 + nt*16 + l16;
        #pragma unroll
        for (int r = 0; r < 4; ++r){
            int o = o0 + quad*4 + r;
            float e = acc[nt][r] + bias[o];
            if (o < HID)            Qt[((size_t)z*N_ + n)*HID + o] = f2bf(e * QPRE);
            else if (o < 2*HID)     Kt[((size_t)z*N_ + n)*HID + (o - HID)] = f2bf(e);
            else                    Vl[((size_t)z*HID + (o - 2*HID))*N_ + n] = f2bf(e);
        }
    }
}

// ---------------------------------------------------------------------------
// K2 (fused): max-free flash attention + output projection + residual.
//   p = exp2(q_pre . k); H_unnorm = P@V (MFMA); rowsum = P@ones (MFMA, same
//   C-layout as H => lane-local normalize). K reg-double-buffered, V loaded
//   early; XCD-swizzled blockIdx for L2 locality of K/V.
__global__ __launch_bounds__(256, 2) void k_attn_out(const u16* __restrict__ Qt,
        const u16* __restrict__ Kt, const u16* __restrict__ Vl,
        const u16* __restrict__ weff,
        const float* __restrict__ ob0, const float* __restrict__ ob1,
        const float* __restrict__ x0, const float* __restrict__ x1,
        float* __restrict__ out){
    // smem: in-loop = per-wave P tiles (wave w at w*16*72, 4*2304B);
    //       post-loop = H tile [64][136] (17408 u16). Overlap via union-style.
    __shared__ __align__(16) u16 smem[64*136];
    int bx = blockIdx.x;                      // 576 = 8 XCD * 72
    int xcd = bx & 7, t = bx >> 3;
    int z  = xcd*2 + (t >= 36 ? 1 : 0);       // XCD x serves z in {2x,2x+1}
    int mt = (t >= 36) ? (t - 36) : t;
    int b = z >> 1, s = z & 1;
    const u16* Q = Qt + (size_t)(b*2 + (1 - s)) * (N_ * HID);
    const u16* K = Kt + (size_t)(b*2 + s)       * (N_ * HID);
    const u16* V = Vl + (size_t)(b*2 + s)       * ((size_t)HID * N_);
    const u16* Wf   = weff + (size_t)s * (C_ * HID);
    const float* bias = s ? ob1 : ob0;
    const float* X = (s ? x1 : x0) + (size_t)b * (C_ * N_);
    float* O = out + (size_t)s * ((size_t)B_ * C_ * N_) + (size_t)b * (C_ * N_);
    int lane = threadIdx.x & 63, wave = threadIdx.x >> 6;
    int l16 = lane & 15, quad = lane >> 4;
    int m0 = mt * 64 + wave * 16;
    u16* pw = smem + wave * (16*72);          // per-wave P tile [16][72]

    bf8 aq[4];
    #pragma unroll
    for (int kk = 0; kk < 4; ++kk)
        aq[kk] = *reinterpret_cast<const bf8*>(&Q[(size_t)(m0 + l16)*HID + kk*32 + quad*8]);

    bf8 ones;
    #pragma unroll
    for (int j = 0; j < 8; ++j) ones[j] = (short)0x3F80;   // bf16 1.0

    f4 oacc[8];
    #pragma unroll
    for (int ct = 0; ct < 8; ++ct) oacc[ct] = f4{0,0,0,0};
    f4 sumacc = f4{0,0,0,0};

    bf8 kfa[16], kfb[16];
    #pragma unroll
    for (int kk = 0; kk < 4; ++kk)
        #pragma unroll
        for (int nt = 0; nt < 4; ++nt)
            kfa[kk*4+nt] = *reinterpret_cast<const bf8*>(&K[(size_t)(nt*16 + l16)*HID + kk*32 + quad*8]);

    auto chunk = [&](bf8 (&kcur)[16], bf8 (&knext)[16], int n0, bool prefetch){
        // V group 0 early (consumed after softmax, ~300 cyc later)
        bf8 vf0[8], vf1[8];
        #pragma unroll
        for (int ct = 0; ct < 8; ++ct)
            vf0[ct] = *reinterpret_cast<const bf8*>(&V[(size_t)(ct*16 + l16)*N_ + n0 + quad*8]);
        // QK
        f4 sacc[4] = {f4{0,0,0,0}, f4{0,0,0,0}, f4{0,0,0,0}, f4{0,0,0,0}};
        #pragma unroll
        for (int kk = 0; kk < 4; ++kk)
            #pragma unroll
            for (int nt = 0; nt < 4; ++nt)
                sacc[nt] = MFMA(aq[kk], kcur[kk*4+nt], sacc[nt]);
        // prefetch next chunk's K (kcur now dead)
        if (prefetch){
            #pragma unroll
            for (int kk = 0; kk < 4; ++kk)
                #pragma unroll
                for (int nt = 0; nt < 4; ++nt)
                    knext[kk*4+nt] = *reinterpret_cast<const bf8*>(&K[(size_t)(n0 + 64 + nt*16 + l16)*HID + kk*32 + quad*8]);
        }
        // V group 1
        #pragma unroll
        for (int ct = 0; ct < 8; ++ct)
            vf1[ct] = *reinterpret_cast<const bf8*>(&V[(size_t)(ct*16 + l16)*N_ + n0 + 32 + quad*8]);
        // p = exp2(s), truncating bf16 store to per-wave LDS
        #pragma unroll
        for (int nt = 0; nt < 4; ++nt)
            #pragma unroll
            for (int r = 0; r < 4; ++r)
                pw[(quad*4 + r)*72 + nt*16 + l16] = hi16(fexp2(sacc[nt][r]));
        // PV + rowsum (kk2 = 0 then 1)
        {
            bf8 ap = *reinterpret_cast<const bf8*>(&pw[l16*72 + quad*8]);
            sumacc = MFMA(ap, ones, sumacc);
            #pragma unroll
            for (int ct = 0; ct < 8; ++ct) oacc[ct] = MFMA(ap, vf0[ct], oacc[ct]);
        }
        {
            bf8 ap = *reinterpret_cast<const bf8*>(&pw[l16*72 + 32 + quad*8]);
            sumacc = MFMA(ap, ones, sumacc);
            #pragma unroll
            for (int ct = 0; ct < 8; ++ct) oacc[ct] = MFMA(ap, vf1[ct], oacc[ct]);
        }
    };

    for (int nc = 0; nc < N_/64; nc += 2){
        chunk(kfa, kfb, nc*64,        true);
        chunk(kfb, kfa, nc*64 + 64,   nc + 2 < N_/64);
    }

    // normalize (lane-local: sumacc has identical C-layout) and stash H
    __syncthreads();                           // P region dead in all waves
    float inv[4];
    #pragma unroll
    for (int r = 0; r < 4; ++r) inv[r] = 1.0f / sumacc[r];
    #pragma unroll
    for (int ct = 0; ct < 8; ++ct)
        #pragma unroll
        for (int r = 0; r < 4; ++r)
            smem[(wave*16 + quad*4 + r)*136 + ct*16 + l16] = f2bf(oacc[ct][r] * inv[r]);
    __syncthreads();

    // out GEMM: wave w -> oc [w*64, w*64+64); K = HID = 128
    int mb = mt * 64;
    int oc0 = wave * 64;
    f4 acc2[4][4];
    #pragma unroll
    for (int ot = 0; ot < 4; ++ot)
        #pragma unroll
        for (int nt = 0; nt < 4; ++nt) acc2[ot][nt] = f4{0,0,0,0};
    #pragma unroll
    for (int kk = 0; kk < 4; ++kk){
        bf8 bh[4];
        #pragma unroll
        for (int nt = 0; nt < 4; ++nt)
            bh[nt] = *reinterpret_cast<const bf8*>(&smem[(nt*16 + l16)*136 + kk*32 + quad*8]);
        #pragma unroll
        for (int ot = 0; ot < 4; ++ot){
            bf8 a = *reinterpret_cast<const bf8*>(&Wf[(oc0 + ot*16 + l16)*HID + kk*32 + quad*8]);
            #pragma unroll
            for (int nt = 0; nt < 4; ++nt)
                acc2[ot][nt] = MFMA(a, bh[nt], acc2[ot][nt]);
        }
    }
    #pragma unroll
    for (int ot = 0; ot < 4; ++ot)
        #pragma unroll
        for (int nt = 0; nt < 4; ++nt){
            int m = mb + nt*16 + l16;
            #pragma unroll
            for (int r = 0; r < 4; ++r){
                int oc = oc0 + ot*16 + quad*4 + r;
                O[(size_t)oc*N_ + m] = acc2[ot][nt][r] + bias[oc] + X[(size_t)oc*N_ + m];
            }
        }
}

// ---------------------------------------------------------------------------
extern "C" void kernel_launch(void* const* d_in, const int* in_sizes, int n_in,
                              void* d_out, int out_size, void* d_ws, size_t ws_size,
                              hipStream_t stream){
    const float* x0  = (const float*)d_in[0];
    const float* x1  = (const float*)d_in[1];
    const float* ew0 = (const float*)d_in[2];
    const float* eb0 = (const float*)d_in[3];
    const float* ew1 = (const float*)d_in[4];
    const float* eb1 = (const float*)d_in[5];
    const float* ow0 = (const float*)d_in[6];
    const float* ob0 = (const float*)d_in[7];
    const float* ow1 = (const float*)d_in[8];
    const float* ob1 = (const float*)d_in[9];

    u16* ws = (u16*)d_ws;
    const size_t QT_E = (size_t)16 * N_ * HID;
    u16* Qt   = ws;
    u16* Kt   = Qt + QT_E;
    u16* Vl   = Kt + QT_E;
    u16* Wbf  = Vl + QT_E;
    u16* weff = Wbf + (size_t)2 * O3 * C_;
    u16* Xt   = (u16*)d_out;                  // scratch phase

    k_wcvt     <<<dim3(96, 2),     dim3(256), 0, stream>>>(ew0, ew1, Wbf);
    k_weff     <<<dim3(2),         dim3(256), 0, stream>>>(ow0, ow1, weff);
    k_transpose<<<dim3(36, 4, 16), dim3(256), 0, stream>>>(x0, x1, Xt);
    k_embed    <<<dim3(36, 6, 16), dim3(256), 0, stream>>>(Xt, Wbf, eb0, eb1, Qt, Kt, Vl);
    k_attn_out <<<dim3(576),       dim3(256), 0, stream>>>(Qt, Kt, Vl, weff, ob0, ob1,
                                                           x0, x1, (float*)d_out);
}